// Round 20
// baseline (95.810 us; speedup 1.0000x reference)
//
#include <hip/hip_runtime.h>
#include <hip/hip_bf16.h>
#include <math.h>

#define BN 32
#define NN 2048
#define KK 32
#define DD 16
#define PART_C 64          // per-b partial copies (= n-chunks per b, grid 2048)
#define PART_STRIDE 1056   // per (b,c): [33][32]
#define SCAPS 256          // s copies: one per caps chunk -> plain stores

// ws layout (floats); overlays exploit liveness:
// 0        : partialA [64*32*1056 = 2162688]  (dead after param1)
// 0        : R        [2097152]               (overlay partialA; written by
//                                              estep3 after param2, dead after transp)
// 2162688  : partialB [2162688]               (dead after param2)
// 4325376  : prmA     [33792]                 (dead after estep2)
// 4359168  : prmB     [33792]                 (dead after estep3)
// 0        : s        [4194304]               (overlay; all of the above dead by caps)
// 4392960  : R3       [2097152]
// 6490112  : xpk      [1048576 ushorts = 524288 floats]
// total 7014400 floats = 28.1 MB

typedef __attribute__((ext_vector_type(8))) short bf16x8;
typedef __attribute__((ext_vector_type(16))) float f32x16;

static __device__ __forceinline__ ushort f2bf(float f) {
    unsigned int u = __float_as_uint(f);
    return (ushort)((u + 0x7FFFu + ((u >> 16) & 1u)) >> 16);  // RNE
}

// reduce PART_C=64 partial copies -> ready params prm[b][33][32]:
// j=0: ck, j=1..16: ak[d]=0.5/v, j=17..32: bk[d]=mu/v.
__global__ __launch_bounds__(256) void k_param(const float* __restrict__ partIn,
                                               float* __restrict__ prm) {
    __shared__ float sm[8 * 1056];   // 33 KB
    const int b = blockIdx.x;
    const int t = threadIdx.x;
    const int k = t & 31, grp = t >> 5;
    float acc[33];
#pragma unroll
    for (int j = 0; j < 33; j++) acc[j] = 0.f;
#pragma unroll 2
    for (int c = 0; c < 8; c++) {
        const float* base = partIn + (size_t)(b * PART_C + grp * 8 + c) * PART_STRIDE;
#pragma unroll
        for (int j = 0; j < 33; j++) acc[j] += base[j * 32 + k];
    }
#pragma unroll
    for (int j = 0; j < 33; j++) sm[grp * 1056 + j * 32 + k] = acc[j];
    __syncthreads();
    if (t < 32) {   // t = k
        float N = 0.f;
#pragma unroll
        for (int g = 0; g < 8; g++) N += sm[g * 1056 + t];
        float invN = 1.0f / N;
        float sumlog = 0.f, cacc = 0.f;
        float* pb = prm + (size_t)b * 1056;
#pragma unroll
        for (int d = 0; d < DD; d++) {
            float sx = 0.f, sxx = 0.f;
#pragma unroll
            for (int g = 0; g < 8; g++) {
                sx  += sm[g * 1056 + (1 + d) * 32 + t];
                sxx += sm[g * 1056 + (17 + d) * 32 + t];
            }
            float m_ = sx * invN;
            float v = fmaxf(sxx * invN - m_ * m_, 1e-12f);
            float is = rsqrtf(v);
            float iv = is * is;
            pb[(1 + d) * 32 + t] = 0.5f * iv;    // ak
            pb[(17 + d) * 32 + t] = m_ * iv;     // bk
            cacc = fmaf(m_ * m_, iv, cacc);
            sumlog += __logf(v);
        }
        pb[t] = __logf(N * (1.0f / NN)) - 0.5f * sumlog - 0.5f * cacc;  // ck
    }
}

// ---------- estep body ----------
// logit(x;k) = ck + sum_d x_d*(bk_d - ak_d*x_d).
// MODE 0: 32-n chunk (grid 2048, PART_C=64), writes per-chunk partials.
// MODE 1: 32-n chunk (grid 2048), writes R[b][n][k].
// FIRST 1: params from mu0; FIRST 0: 33 coalesced loads from prm.
template <int MODE, int FIRST>
static __device__ __forceinline__ void estep_body(
    int blk, const float* __restrict__ x, const float* __restrict__ mu0,
    const float* __restrict__ prmIn, float* __restrict__ partOut,
    float* __restrict__ Rout) {
    const int b = blk >> 6;       // 32 b
    const int chunk = blk & 63;   // 64 chunks of 32 n
    const int tid = threadIdx.x;
    const int wave = tid >> 6;
    const int lane = tid & 63;
    const int k = lane & 31;
    const int jj = lane >> 5;

    float ak[DD], bk[DD], ck;
    if (FIRST) {
        float msq = 0.f;
        const float4* mp = (const float4*)(mu0 + (size_t)(b * KK + k) * DD);
#pragma unroll
        for (int q = 0; q < 4; q++) {
            float4 m4 = mp[q];
            bk[q*4+0]=m4.x; bk[q*4+1]=m4.y; bk[q*4+2]=m4.z; bk[q*4+3]=m4.w;
            msq += m4.x*m4.x + m4.y*m4.y + m4.z*m4.z + m4.w*m4.w;
        }
#pragma unroll
        for (int d = 0; d < DD; d++) ak[d] = 0.5f;
        ck = -3.4657359028f - 0.5f * msq;   // log(1/32) - 0.5*sum mu^2
    } else {
        const float* pb = prmIn + (size_t)b * 1056;
        ck = pb[k];
#pragma unroll
        for (int d = 0; d < DD; d++) {
            ak[d] = pb[(1 + d) * 32 + k];
            bk[d] = pb[(17 + d) * 32 + k];
        }
    }

    float aN = 0.f, aSx[DD], aSxx[DD];
#pragma unroll
    for (int d = 0; d < DD; d++) { aSx[d] = 0.f; aSxx[d] = 0.f; }

#pragma unroll 4
    for (int i = 0; i < 4; i++) {
        const int n = chunk * 32 + i * 8 + wave * 2 + jj;
        const float4* xp = (const float4*)(x + ((size_t)b * NN + n) * DD);
        float xv[DD];
#pragma unroll
        for (int q = 0; q < 4; q++) {
            float4 v = xp[q];
            xv[q*4+0]=v.x; xv[q*4+1]=v.y; xv[q*4+2]=v.z; xv[q*4+3]=v.w;
        }
        float logit = ck;
#pragma unroll
        for (int d = 0; d < DD; d++) {
            float t1 = fmaf(-ak[d], xv[d], bk[d]);
            logit = fmaf(xv[d], t1, logit);
        }
        float m = logit;
#pragma unroll
        for (int off = 1; off < 32; off <<= 1) m = fmaxf(m, __shfl_xor(m, off));
        float e = __expf(logit - m);
        float ssum = e;
#pragma unroll
        for (int off = 1; off < 32; off <<= 1) ssum += __shfl_xor(ssum, off);
        float g = e * __builtin_amdgcn_rcpf(ssum);

        if (MODE == 1) {
            Rout[((size_t)b * NN + n) * KK + k] = g;  // coalesced per half-wave
        } else {
            aN += g;
#pragma unroll
            for (int d = 0; d < DD; d++) {
                aSx[d] = fmaf(g, xv[d], aSx[d]);
                aSxx[d] = fmaf(g * xv[d], xv[d], aSxx[d]);
            }
        }
    }

    if (MODE == 0) {
        __shared__ float red[4][KK * 33];
        aN += __shfl_xor(aN, 32);
#pragma unroll
        for (int d = 0; d < DD; d++) {
            aSx[d] += __shfl_xor(aSx[d], 32);
            aSxx[d] += __shfl_xor(aSxx[d], 32);
        }
        if (jj == 0) {
            red[wave][k * 33 + 0] = aN;
#pragma unroll
            for (int d = 0; d < DD; d++) {
                red[wave][k * 33 + 1 + d] = aSx[d];
                red[wave][k * 33 + 17 + d] = aSxx[d];
            }
        }
        __syncthreads();
        float* outp = partOut + (size_t)(b * PART_C + chunk) * PART_STRIDE;
        for (int idx = tid; idx < KK * 33; idx += 256) {
            int kk = idx & 31, j = idx >> 5;
            float v = red[0][kk * 33 + j] + red[1][kk * 33 + j] +
                      red[2][kk * 33 + j] + red[3][kk * 33 + j];
            outp[idx] = v;
        }
    }
}

static __device__ __forceinline__ void xpack_body(int blk, const float* __restrict__ x,
                                                  ushort* __restrict__ xpk) {
    int idx = blk * 256 + threadIdx.x;   // n*64 + l
    int n = idx >> 6, l = idx & 63;
    int b = l & 31, e0 = (l >> 5) * 8;
    const float4* xp = (const float4*)(x + ((size_t)b * NN + n) * DD + e0);
    float4 a = xp[0], c = xp[1];
    ushort* o = xpk + (size_t)idx * 8;
    o[0]=f2bf(a.x); o[1]=f2bf(a.y); o[2]=f2bf(a.z); o[3]=f2bf(a.w);
    o[4]=f2bf(c.x); o[5]=f2bf(c.y); o[6]=f2bf(c.z); o[7]=f2bf(c.w);
}

__global__ __launch_bounds__(256, 4) void k_fused1(
    const float* __restrict__ x, const float* __restrict__ mu0,
    float* __restrict__ partOut, ushort* __restrict__ xpk) {
    if (blockIdx.x < 2048)
        estep_body<0, 1>(blockIdx.x, x, mu0, nullptr, partOut, nullptr);
    else
        xpack_body(blockIdx.x - 2048, x, xpk);
}

template <int MODE>
__global__ __launch_bounds__(256, 4) void k_estep(
    const float* __restrict__ x, const float* __restrict__ prmIn,
    float* __restrict__ partOut, float* __restrict__ Rout) {
    estep_body<MODE, 0>(blockIdx.x, x, nullptr, prmIn, partOut, Rout);
}

// transpose R[b][n][k] -> R3[n][k][hi][pos] via LDS; both global sides coalesced.
__global__ __launch_bounds__(256) void k_transp(const float* __restrict__ R,
                                                float* __restrict__ R3) {
    __shared__ float lds[32 * 8 * 32];  // [b][nj][k], 32 KB
    const int t = threadIdx.x;
    const int n0 = blockIdx.x * 8;
#pragma unroll
    for (int c = 0; c < 8; c++) {
        int f = c * 256 + t;             // float4 index (2048 total)
        int b = f >> 6, rem = f & 63;
        int nj = rem >> 3, k4 = rem & 7;
        float4 v = *(const float4*)(R + ((size_t)b * NN + n0 + nj) * KK + k4 * 4);
        *(float4*)&lds[(b * 8 + nj) * 32 + k4 * 4] = v;
    }
    __syncthreads();
#pragma unroll
    for (int c = 0; c < 8; c++) {
        int o = c * 256 + t;             // output float4 index
        int a4 = o * 4;
        int nl = a4 >> 10, w = a4 & 1023;
        int k = w >> 5, hi = (w >> 4) & 1, p = (w >> 2) & 3;
        int bb = 8 * p + 4 * hi;         // pos 4p+e -> b = e + 8p + 4hi
        float4 v;
        v.x = lds[((bb + 0) * 8 + nl) * 32 + k];
        v.y = lds[((bb + 1) * 8 + nl) * 32 + k];
        v.z = lds[((bb + 2) * 8 + nl) * 32 + k];
        v.w = lds[((bb + 3) * 8 + nl) * 32 + k];
        *(float4*)(R3 + (size_t)n0 * 1024 + a4) = v;
    }
}

// caps v8: per (wave, n) one mfma_32x32x16_bf16; r from fragment-ordered R3;
// plain stores into per-chunk s copy (SCAPS=256), no atomics, no zeroing.
__global__ __launch_bounds__(256, 4) void k_caps(
    const float* __restrict__ W, const ushort* __restrict__ xpk,
    const float* __restrict__ R3, float* __restrict__ s) {
    const int tid = threadIdx.x;
    const int wv = tid >> 6, l = tid & 63;
    const int chunk = blockIdx.x >> 2, tg = blockIdx.x & 3;
    const int t = tg * 4 + wv;          // kd-tile 0..15
    const int col = l & 31, hi = l >> 5;
    const int kq = (l >> 4) & 1;        // k = 2t + kq
    float* sc = s + (size_t)chunk * (BN * KK * DD);

    float sacc[16];
#pragma unroll
    for (int q = 0; q < 16; q++) sacc[q] = 0.f;
    const f32x16 zacc = {0.f,0.f,0.f,0.f, 0.f,0.f,0.f,0.f,
                         0.f,0.f,0.f,0.f, 0.f,0.f,0.f,0.f};

#pragma unroll 2
    for (int i = 0; i < 8; i++) {
        const int n = chunk * 8 + i;
        bf16x8 af = *(const bf16x8*)(xpk + ((size_t)n * 64 + l) * 8);
        const float4* wp = (const float4*)(W + (((size_t)n * 512 + t * 32 + col) * DD) + hi * 8);
        float4 wlo = wp[0], whi = wp[1];
        bf16x8 bfr;
        bfr[0]=(short)f2bf(wlo.x); bfr[1]=(short)f2bf(wlo.y);
        bfr[2]=(short)f2bf(wlo.z); bfr[3]=(short)f2bf(wlo.w);
        bfr[4]=(short)f2bf(whi.x); bfr[5]=(short)f2bf(whi.y);
        bfr[6]=(short)f2bf(whi.z); bfr[7]=(short)f2bf(whi.w);
        const float4* rp = (const float4*)(R3 + (((size_t)n * KK + 2 * t + kq) * 2 + hi) * 16);
        float4 r0 = rp[0], r1 = rp[1], r2 = rp[2], r3v = rp[3];

        f32x16 D = __builtin_amdgcn_mfma_f32_32x32x16_bf16(af, bfr, zacc, 0, 0, 0);

        sacc[0]  = fmaf(r0.x,  D[0],  sacc[0]);
        sacc[1]  = fmaf(r0.y,  D[1],  sacc[1]);
        sacc[2]  = fmaf(r0.z,  D[2],  sacc[2]);
        sacc[3]  = fmaf(r0.w,  D[3],  sacc[3]);
        sacc[4]  = fmaf(r1.x,  D[4],  sacc[4]);
        sacc[5]  = fmaf(r1.y,  D[5],  sacc[5]);
        sacc[6]  = fmaf(r1.z,  D[6],  sacc[6]);
        sacc[7]  = fmaf(r1.w,  D[7],  sacc[7]);
        sacc[8]  = fmaf(r2.x,  D[8],  sacc[8]);
        sacc[9]  = fmaf(r2.y,  D[9],  sacc[9]);
        sacc[10] = fmaf(r2.z,  D[10], sacc[10]);
        sacc[11] = fmaf(r2.w,  D[11], sacc[11]);
        sacc[12] = fmaf(r3v.x, D[12], sacc[12]);
        sacc[13] = fmaf(r3v.y, D[13], sacc[13]);
        sacc[14] = fmaf(r3v.z, D[14], sacc[14]);
        sacc[15] = fmaf(r3v.w, D[15], sacc[15]);
    }

    const int kd = t * 32 + col;
#pragma unroll
    for (int q = 0; q < 16; q++) {
        const int b = (q & 3) + 8 * (q >> 2) + 4 * hi;  // verified C/D row map
        sc[(size_t)b * (KK * DD) + kd] = sacc[q];       // disjoint plain store
    }
}

// one wave per block, 256 blocks; thread per (b,k,d).
__global__ __launch_bounds__(64) void k_squash(const float* __restrict__ s,
                                               float* __restrict__ out) {
    int idx = blockIdx.x * 64 + threadIdx.x;  // 16384 = BN*KK*DD
    float v = 0.f;
#pragma unroll 16
    for (int c = 0; c < SCAPS; c++) v += s[(size_t)c * (BN * KK * DD) + idx];
    float ss = v * v;
#pragma unroll
    for (int off = 1; off < 16; off <<= 1) ss += __shfl_xor(ss, off);
    ss += 1e-7f;
    float scale = sqrtf(ss) / (1.0f + ss);
    out[idx] = v * scale;
}

extern "C" void kernel_launch(void* const* d_in, const int* in_sizes, int n_in,
                              void* d_out, int out_size, void* d_ws, size_t ws_size,
                              hipStream_t stream) {
    const float* x   = (const float*)d_in[0];
    const float* W   = (const float*)d_in[1];
    const float* mu0 = (const float*)d_in[2];
    float* ws    = (float*)d_ws;
    float* partA = ws;                 // dead after param1
    float* partB = ws + 2162688;       // dead after param2
    float* prmA  = ws + 4325376;       // dead after estep2
    float* prmB  = ws + 4359168;       // dead after estep3
    float* R     = ws;                 // overlays partA (estep3 runs after param1)
    float* s     = ws;                 // overlays everything dead by caps
    float* R3    = ws + 4392960;
    ushort* xpk  = (ushort*)(ws + 6490112);

    // 1: EM iter1 partials (grid 2048) + x bf16 pack (512), fused
    k_fused1<<<2560, 256, 0, stream>>>(x, mu0, partA, xpk);
    // 2: reduce 64 partials -> ready params (iter2)
    k_param<<<32, 256, 0, stream>>>(partA, prmA);
    // 3: EM iter2 (reads prmA, grid 2048) -> partB
    k_estep<0><<<2048, 256, 0, stream>>>(x, prmA, partB, nullptr);
    // 4: reduce 64 partials -> ready params (iter3)
    k_param<<<32, 256, 0, stream>>>(partB, prmB);
    // 5: EM iter3 (reads prmB, grid 2048) -> R (overlays dead partialA)
    k_estep<1><<<2048, 256, 0, stream>>>(x, prmB, nullptr, R);
    // 6: transpose R -> fragment-ordered R3 (LDS, coalesced both sides)
    k_transp<<<256, 256, 0, stream>>>(R, R3);
    // 7: caps einsum (MFMA v8), plain stores into per-chunk s copies
    k_caps<<<1024, 256, 0, stream>>>(W, xpk, R3, s);
    // 8: reduce 256 copies + squash
    k_squash<<<256, 64, 0, stream>>>(s, (float*)d_out);
}

// Round 21
// 84.736 us; speedup vs baseline: 1.1307x; 1.1307x over previous
//
#include <hip/hip_runtime.h>
#include <hip/hip_bf16.h>
#include <math.h>

#define BN 32
#define NN 2048
#define KK 32
#define DD 16
#define PART_C 32          // per-b partial copies (= n-chunks per b)
#define PART_STRIDE 1056   // per (b,c): [33][32]
#define SCAPS 256          // s copies: one per caps chunk -> plain stores

// ws layout (floats); s overlays regions dead by caps time:
// 0        : partialA [32*32*1056 = 1081344]  (dead after param1)
// 1081344  : partialB [1081344]               (dead after param2)
// 2162688  : prmA     [33792]                 (dead after estep2)
// 2196480  : prmB     [33792]                 (dead after estep3)
// 2230272  : R        [2097152]               (dead after transp)
// 0        : s        [4194304]               (overlay; all above dead by caps)
// 4327424  : R3       [2097152]
// 6424576  : xpk      [1048576 ushorts = 524288 floats]

typedef __attribute__((ext_vector_type(8))) short bf16x8;
typedef __attribute__((ext_vector_type(16))) float f32x16;

static __device__ __forceinline__ ushort f2bf(float f) {
    unsigned int u = __float_as_uint(f);
    return (ushort)((u + 0x7FFFu + ((u >> 16) & 1u)) >> 16);  // RNE
}

// reduce PART_C=32 partial copies -> ready params prm[b][33][32]
__global__ __launch_bounds__(256) void k_param(const float* __restrict__ partIn,
                                               float* __restrict__ prm) {
    __shared__ float sm[8 * 1056];   // 33 KB
    const int b = blockIdx.x;
    const int t = threadIdx.x;
    const int k = t & 31, grp = t >> 5;
    float acc[33];
#pragma unroll
    for (int j = 0; j < 33; j++) acc[j] = 0.f;
#pragma unroll
    for (int c = 0; c < 4; c++) {
        const float* base = partIn + (size_t)(b * PART_C + grp * 4 + c) * PART_STRIDE;
#pragma unroll
        for (int j = 0; j < 33; j++) acc[j] += base[j * 32 + k];
    }
#pragma unroll
    for (int j = 0; j < 33; j++) sm[grp * 1056 + j * 32 + k] = acc[j];
    __syncthreads();
    if (t < 32) {   // t = k
        float N = 0.f;
#pragma unroll
        for (int g = 0; g < 8; g++) N += sm[g * 1056 + t];
        float invN = 1.0f / N;
        float sumlog = 0.f, cacc = 0.f;
        float* pb = prm + (size_t)b * 1056;
#pragma unroll
        for (int d = 0; d < DD; d++) {
            float sx = 0.f, sxx = 0.f;
#pragma unroll
            for (int g = 0; g < 8; g++) {
                sx  += sm[g * 1056 + (1 + d) * 32 + t];
                sxx += sm[g * 1056 + (17 + d) * 32 + t];
            }
            float m_ = sx * invN;
            float v = fmaxf(sxx * invN - m_ * m_, 1e-12f);
            float is = rsqrtf(v);
            float iv = is * is;
            pb[(1 + d) * 32 + t] = 0.5f * iv;    // ak
            pb[(17 + d) * 32 + t] = m_ * iv;     // bk
            cacc = fmaf(m_ * m_, iv, cacc);
            sumlog += __logf(v);
        }
        pb[t] = __logf(N * (1.0f / NN)) - 0.5f * sumlog - 0.5f * cacc;  // ck
    }
}

// ---------- estep body (R19-verbatim) ----------
// MODE 0: 64-n chunk (grid 1024, PART_C=32). MODE 1: 32-n chunk (grid 2048).
template <int MODE, int FIRST>
static __device__ __forceinline__ void estep_body(
    int blk, const float* __restrict__ x, const float* __restrict__ mu0,
    const float* __restrict__ prmIn, float* __restrict__ partOut,
    float* __restrict__ Rout) {
    const int b = (MODE == 0) ? (blk >> 5) : (blk >> 6);
    const int chunk = (MODE == 0) ? (blk & 31) : (blk & 63);
    const int tid = threadIdx.x;
    const int wave = tid >> 6;
    const int lane = tid & 63;
    const int k = lane & 31;
    const int jj = lane >> 5;

    float ak[DD], bk[DD], ck;
    if (FIRST) {
        float msq = 0.f;
        const float4* mp = (const float4*)(mu0 + (size_t)(b * KK + k) * DD);
#pragma unroll
        for (int q = 0; q < 4; q++) {
            float4 m4 = mp[q];
            bk[q*4+0]=m4.x; bk[q*4+1]=m4.y; bk[q*4+2]=m4.z; bk[q*4+3]=m4.w;
            msq += m4.x*m4.x + m4.y*m4.y + m4.z*m4.z + m4.w*m4.w;
        }
#pragma unroll
        for (int d = 0; d < DD; d++) ak[d] = 0.5f;
        ck = -3.4657359028f - 0.5f * msq;   // log(1/32) - 0.5*sum mu^2
    } else {
        const float* pb = prmIn + (size_t)b * 1056;
        ck = pb[k];
#pragma unroll
        for (int d = 0; d < DD; d++) {
            ak[d] = pb[(1 + d) * 32 + k];
            bk[d] = pb[(17 + d) * 32 + k];
        }
    }

    float aN = 0.f, aSx[DD], aSxx[DD];
#pragma unroll
    for (int d = 0; d < DD; d++) { aSx[d] = 0.f; aSxx[d] = 0.f; }

    const int NITER = (MODE == 0) ? 8 : 4;
#pragma unroll 4
    for (int i = 0; i < NITER; i++) {
        const int n = chunk * ((MODE == 0) ? 64 : 32) + i * 8 + wave * 2 + jj;
        const float4* xp = (const float4*)(x + ((size_t)b * NN + n) * DD);
        float xv[DD];
#pragma unroll
        for (int q = 0; q < 4; q++) {
            float4 v = xp[q];
            xv[q*4+0]=v.x; xv[q*4+1]=v.y; xv[q*4+2]=v.z; xv[q*4+3]=v.w;
        }
        float logit = ck;
#pragma unroll
        for (int d = 0; d < DD; d++) {
            float t1 = fmaf(-ak[d], xv[d], bk[d]);
            logit = fmaf(xv[d], t1, logit);
        }
        float m = logit;
#pragma unroll
        for (int off = 1; off < 32; off <<= 1) m = fmaxf(m, __shfl_xor(m, off));
        float e = __expf(logit - m);
        float ssum = e;
#pragma unroll
        for (int off = 1; off < 32; off <<= 1) ssum += __shfl_xor(ssum, off);
        float g = e * __builtin_amdgcn_rcpf(ssum);

        if (MODE == 1) {
            Rout[((size_t)b * NN + n) * KK + k] = g;  // coalesced per half-wave
        } else {
            aN += g;
#pragma unroll
            for (int d = 0; d < DD; d++) {
                aSx[d] = fmaf(g, xv[d], aSx[d]);
                aSxx[d] = fmaf(g * xv[d], xv[d], aSxx[d]);
            }
        }
    }

    if (MODE == 0) {
        __shared__ float red[4][KK * 33];
        aN += __shfl_xor(aN, 32);
#pragma unroll
        for (int d = 0; d < DD; d++) {
            aSx[d] += __shfl_xor(aSx[d], 32);
            aSxx[d] += __shfl_xor(aSxx[d], 32);
        }
        if (jj == 0) {
            red[wave][k * 33 + 0] = aN;
#pragma unroll
            for (int d = 0; d < DD; d++) {
                red[wave][k * 33 + 1 + d] = aSx[d];
                red[wave][k * 33 + 17 + d] = aSxx[d];
            }
        }
        __syncthreads();
        float* outp = partOut + (size_t)(b * PART_C + chunk) * PART_STRIDE;
        for (int idx = tid; idx < KK * 33; idx += 256) {
            int kk = idx & 31, j = idx >> 5;
            float v = red[0][kk * 33 + j] + red[1][kk * 33 + j] +
                      red[2][kk * 33 + j] + red[3][kk * 33 + j];
            outp[idx] = v;
        }
    }
}

static __device__ __forceinline__ void xpack_body(int blk, const float* __restrict__ x,
                                                  ushort* __restrict__ xpk) {
    int idx = blk * 256 + threadIdx.x;   // n*64 + l
    int n = idx >> 6, l = idx & 63;
    int b = l & 31, e0 = (l >> 5) * 8;
    const float4* xp = (const float4*)(x + ((size_t)b * NN + n) * DD + e0);
    float4 a = xp[0], c = xp[1];
    ushort* o = xpk + (size_t)idx * 8;
    o[0]=f2bf(a.x); o[1]=f2bf(a.y); o[2]=f2bf(a.z); o[3]=f2bf(a.w);
    o[4]=f2bf(c.x); o[5]=f2bf(c.y); o[6]=f2bf(c.z); o[7]=f2bf(c.w);
}

__global__ __launch_bounds__(256, 4) void k_fused1(
    const float* __restrict__ x, const float* __restrict__ mu0,
    float* __restrict__ partOut, ushort* __restrict__ xpk) {
    if (blockIdx.x < 1024)
        estep_body<0, 1>(blockIdx.x, x, mu0, nullptr, partOut, nullptr);
    else
        xpack_body(blockIdx.x - 1024, x, xpk);
}

template <int MODE>
__global__ __launch_bounds__(256, 4) void k_estep(
    const float* __restrict__ x, const float* __restrict__ prmIn,
    float* __restrict__ partOut, float* __restrict__ Rout) {
    estep_body<MODE, 0>(blockIdx.x, x, nullptr, prmIn, partOut, Rout);
}

// transpose R[b][n][k] -> R3[n][k][hi][pos]; 512 blocks x 4 n (2 blocks/CU).
__global__ __launch_bounds__(256) void k_transp(const float* __restrict__ R,
                                                float* __restrict__ R3) {
    __shared__ float lds[32 * 4 * 32];  // [b][nj][k], 16 KB
    const int t = threadIdx.x;
    const int n0 = blockIdx.x * 4;
#pragma unroll
    for (int c = 0; c < 4; c++) {
        int f = c * 256 + t;             // float4 index (1024 total)
        int b = f >> 5, rem = f & 31;
        int nj = rem >> 3, k4 = rem & 7;
        float4 v = *(const float4*)(R + ((size_t)b * NN + n0 + nj) * KK + k4 * 4);
        *(float4*)&lds[(b * 4 + nj) * 32 + k4 * 4] = v;
    }
    __syncthreads();
#pragma unroll
    for (int c = 0; c < 4; c++) {
        int o = c * 256 + t;             // output float4 index
        int a4 = o * 4;
        int nl = a4 >> 10, w = a4 & 1023;
        int k = w >> 5, hi = (w >> 4) & 1, p = (w >> 2) & 3;
        int bb = 8 * p + 4 * hi;         // pos 4p+e -> b = e + 8p + 4hi
        float4 v;
        v.x = lds[((bb + 0) * 4 + nl) * 32 + k];
        v.y = lds[((bb + 1) * 4 + nl) * 32 + k];
        v.z = lds[((bb + 2) * 4 + nl) * 32 + k];
        v.w = lds[((bb + 3) * 4 + nl) * 32 + k];
        *(float4*)(R3 + (size_t)n0 * 1024 + a4) = v;
    }
}

// caps v8: per (wave, n) one mfma_32x32x16_bf16; r from fragment-ordered R3;
// plain stores into per-chunk s copy (SCAPS=256), no atomics, no zeroing.
__global__ __launch_bounds__(256, 4) void k_caps(
    const float* __restrict__ W, const ushort* __restrict__ xpk,
    const float* __restrict__ R3, float* __restrict__ s) {
    const int tid = threadIdx.x;
    const int wv = tid >> 6, l = tid & 63;
    const int chunk = blockIdx.x >> 2, tg = blockIdx.x & 3;
    const int t = tg * 4 + wv;          // kd-tile 0..15
    const int col = l & 31, hi = l >> 5;
    const int kq = (l >> 4) & 1;        // k = 2t + kq
    float* sc = s + (size_t)chunk * (BN * KK * DD);

    float sacc[16];
#pragma unroll
    for (int q = 0; q < 16; q++) sacc[q] = 0.f;
    const f32x16 zacc = {0.f,0.f,0.f,0.f, 0.f,0.f,0.f,0.f,
                         0.f,0.f,0.f,0.f, 0.f,0.f,0.f,0.f};

#pragma unroll 2
    for (int i = 0; i < 8; i++) {
        const int n = chunk * 8 + i;
        bf16x8 af = *(const bf16x8*)(xpk + ((size_t)n * 64 + l) * 8);
        const float4* wp = (const float4*)(W + (((size_t)n * 512 + t * 32 + col) * DD) + hi * 8);
        float4 wlo = wp[0], whi = wp[1];
        bf16x8 bfr;
        bfr[0]=(short)f2bf(wlo.x); bfr[1]=(short)f2bf(wlo.y);
        bfr[2]=(short)f2bf(wlo.z); bfr[3]=(short)f2bf(wlo.w);
        bfr[4]=(short)f2bf(whi.x); bfr[5]=(short)f2bf(whi.y);
        bfr[6]=(short)f2bf(whi.z); bfr[7]=(short)f2bf(whi.w);
        const float4* rp = (const float4*)(R3 + (((size_t)n * KK + 2 * t + kq) * 2 + hi) * 16);
        float4 r0 = rp[0], r1 = rp[1], r2 = rp[2], r3v = rp[3];

        f32x16 D = __builtin_amdgcn_mfma_f32_32x32x16_bf16(af, bfr, zacc, 0, 0, 0);

        sacc[0]  = fmaf(r0.x,  D[0],  sacc[0]);
        sacc[1]  = fmaf(r0.y,  D[1],  sacc[1]);
        sacc[2]  = fmaf(r0.z,  D[2],  sacc[2]);
        sacc[3]  = fmaf(r0.w,  D[3],  sacc[3]);
        sacc[4]  = fmaf(r1.x,  D[4],  sacc[4]);
        sacc[5]  = fmaf(r1.y,  D[5],  sacc[5]);
        sacc[6]  = fmaf(r1.z,  D[6],  sacc[6]);
        sacc[7]  = fmaf(r1.w,  D[7],  sacc[7]);
        sacc[8]  = fmaf(r2.x,  D[8],  sacc[8]);
        sacc[9]  = fmaf(r2.y,  D[9],  sacc[9]);
        sacc[10] = fmaf(r2.z,  D[10], sacc[10]);
        sacc[11] = fmaf(r2.w,  D[11], sacc[11]);
        sacc[12] = fmaf(r3v.x, D[12], sacc[12]);
        sacc[13] = fmaf(r3v.y, D[13], sacc[13]);
        sacc[14] = fmaf(r3v.z, D[14], sacc[14]);
        sacc[15] = fmaf(r3v.w, D[15], sacc[15]);
    }

    const int kd = t * 32 + col;
#pragma unroll
    for (int q = 0; q < 16; q++) {
        const int b = (q & 3) + 8 * (q >> 2) + 4 * hi;  // verified C/D row map
        sc[(size_t)b * (KK * DD) + kd] = sacc[q];       // disjoint plain store
    }
}

// squash: block = 64 outputs x 4 copy-quarters (256 thr); each thread sums 64
// copies, LDS-reduce quarters, 16-lane shuffle for the d-norm. 4 waves/CU.
__global__ __launch_bounds__(256) void k_squash(const float* __restrict__ s,
                                                float* __restrict__ out) {
    __shared__ float sq[256];
    const int t = threadIdx.x;
    const int il = t & 63, qt = t >> 6;
    const int idx = blockIdx.x * 64 + il;   // 16384 = BN*KK*DD
    float v = 0.f;
#pragma unroll 16
    for (int c = qt * 64; c < qt * 64 + 64; c++)
        v += s[(size_t)c * (BN * KK * DD) + idx];
    sq[t] = v;
    __syncthreads();
    if (qt == 0) {
        v = sq[il] + sq[il + 64] + sq[il + 128] + sq[il + 192];
        float ss = v * v;
#pragma unroll
        for (int off = 1; off < 16; off <<= 1) ss += __shfl_xor(ss, off);
        ss += 1e-7f;
        float scale = sqrtf(ss) / (1.0f + ss);
        out[idx] = v * scale;
    }
}

extern "C" void kernel_launch(void* const* d_in, const int* in_sizes, int n_in,
                              void* d_out, int out_size, void* d_ws, size_t ws_size,
                              hipStream_t stream) {
    const float* x   = (const float*)d_in[0];
    const float* W   = (const float*)d_in[1];
    const float* mu0 = (const float*)d_in[2];
    float* ws    = (float*)d_ws;
    float* partA = ws;
    float* partB = ws + 1081344;
    float* prmA  = ws + 2162688;
    float* prmB  = ws + 2196480;
    float* R     = ws + 2230272;
    float* s     = ws;            // overlays partA/partB/prm/R (all dead by caps)
    float* R3    = ws + 4327424;
    ushort* xpk  = (ushort*)(ws + 6424576);

    // 1: EM iter1 partials (grid 1024) + x bf16 pack (512), fused
    k_fused1<<<1536, 256, 0, stream>>>(x, mu0, partA, xpk);
    // 2: reduce 32 partials -> ready params (iter2)
    k_param<<<32, 256, 0, stream>>>(partA, prmA);
    // 3: EM iter2 (reads prmA, grid 1024) -> partB
    k_estep<0><<<1024, 256, 0, stream>>>(x, prmA, partB, nullptr);
    // 4: reduce 32 partials -> ready params (iter3)
    k_param<<<32, 256, 0, stream>>>(partB, prmB);
    // 5: EM iter3 (reads prmB, grid 2048) -> R
    k_estep<1><<<2048, 256, 0, stream>>>(x, prmB, nullptr, R);
    // 6: transpose R -> fragment-ordered R3 (512 blocks x 4 n)
    k_transp<<<512, 256, 0, stream>>>(R, R3);
    // 7: caps einsum (MFMA v8), plain stores into per-chunk s copies
    k_caps<<<1024, 256, 0, stream>>>(W, xpk, R3, s);
    // 8: reduce 256 copies + squash (256 blocks x 4 waves)
    k_squash<<<256, 256, 0, stream>>>(s, (float*)d_out);
}

// Round 22
// 83.238 us; speedup vs baseline: 1.1510x; 1.0180x over previous
//
#include <hip/hip_runtime.h>
#include <hip/hip_bf16.h>
#include <math.h>

#define BN 32
#define NN 2048
#define KK 32
#define DD 16
#define PART_C 32          // per-b partial copies (= n-chunks per b)
#define PART_STRIDE 1056   // per (b,c): [33][32]
#define SCAPS 256          // s copies: one per caps chunk -> plain stores

// ws layout (floats); s overlays regions dead by caps time:
// 0        : partialA [32*32*1056 = 1081344]  (dead after param1)
// 1081344  : partialB [1081344]               (dead after param2)
// 2162688  : prmA     [33792]                 (dead after estep2)
// 2196480  : prmB     [33792]                 (dead after estep3)
// 2230272  : R        [2097152]               (dead after transp)
// 0        : s        [4194304]               (overlay; all above dead by caps)
// 4327424  : R3       [2097152]
// 6424576  : xpk      [1048576 ushorts = 524288 floats]

typedef __attribute__((ext_vector_type(8))) short bf16x8;
typedef __attribute__((ext_vector_type(16))) float f32x16;

static __device__ __forceinline__ ushort f2bf(float f) {
    unsigned int u = __float_as_uint(f);
    return (ushort)((u + 0x7FFFu + ((u >> 16) & 1u)) >> 16);  // RNE
}
static __device__ __forceinline__ short f2bfs(float f) {
    __hip_bfloat16 h = __float2bfloat16(f);  // HW RNE cvt (pairs to v_cvt_pk)
    return *reinterpret_cast<short*>(&h);
}

// reduce PART_C=32 partial copies -> ready params prm[b][33][32]
__global__ __launch_bounds__(256) void k_param(const float* __restrict__ partIn,
                                               float* __restrict__ prm) {
    __shared__ float sm[8 * 1056];   // 33 KB
    const int b = blockIdx.x;
    const int t = threadIdx.x;
    const int k = t & 31, grp = t >> 5;
    float acc[33];
#pragma unroll
    for (int j = 0; j < 33; j++) acc[j] = 0.f;
#pragma unroll
    for (int c = 0; c < 4; c++) {
        const float* base = partIn + (size_t)(b * PART_C + grp * 4 + c) * PART_STRIDE;
#pragma unroll
        for (int j = 0; j < 33; j++) acc[j] += base[j * 32 + k];
    }
#pragma unroll
    for (int j = 0; j < 33; j++) sm[grp * 1056 + j * 32 + k] = acc[j];
    __syncthreads();
    if (t < 32) {   // t = k
        float N = 0.f;
#pragma unroll
        for (int g = 0; g < 8; g++) N += sm[g * 1056 + t];
        float invN = 1.0f / N;
        float sumlog = 0.f, cacc = 0.f;
        float* pb = prm + (size_t)b * 1056;
#pragma unroll
        for (int d = 0; d < DD; d++) {
            float sx = 0.f, sxx = 0.f;
#pragma unroll
            for (int g = 0; g < 8; g++) {
                sx  += sm[g * 1056 + (1 + d) * 32 + t];
                sxx += sm[g * 1056 + (17 + d) * 32 + t];
            }
            float m_ = sx * invN;
            float v = fmaxf(sxx * invN - m_ * m_, 1e-12f);
            float is = rsqrtf(v);
            float iv = is * is;
            pb[(1 + d) * 32 + t] = 0.5f * iv;    // ak
            pb[(17 + d) * 32 + t] = m_ * iv;     // bk
            cacc = fmaf(m_ * m_, iv, cacc);
            sumlog += __logf(v);
        }
        pb[t] = __logf(N * (1.0f / NN)) - 0.5f * sumlog - 0.5f * cacc;  // ck
    }
}

// ---------- estep body (R19/R21-verbatim) ----------
// MODE 0: 64-n chunk (grid 1024, PART_C=32). MODE 1: 32-n chunk (grid 2048).
template <int MODE, int FIRST>
static __device__ __forceinline__ void estep_body(
    int blk, const float* __restrict__ x, const float* __restrict__ mu0,
    const float* __restrict__ prmIn, float* __restrict__ partOut,
    float* __restrict__ Rout) {
    const int b = (MODE == 0) ? (blk >> 5) : (blk >> 6);
    const int chunk = (MODE == 0) ? (blk & 31) : (blk & 63);
    const int tid = threadIdx.x;
    const int wave = tid >> 6;
    const int lane = tid & 63;
    const int k = lane & 31;
    const int jj = lane >> 5;

    float ak[DD], bk[DD], ck;
    if (FIRST) {
        float msq = 0.f;
        const float4* mp = (const float4*)(mu0 + (size_t)(b * KK + k) * DD);
#pragma unroll
        for (int q = 0; q < 4; q++) {
            float4 m4 = mp[q];
            bk[q*4+0]=m4.x; bk[q*4+1]=m4.y; bk[q*4+2]=m4.z; bk[q*4+3]=m4.w;
            msq += m4.x*m4.x + m4.y*m4.y + m4.z*m4.z + m4.w*m4.w;
        }
#pragma unroll
        for (int d = 0; d < DD; d++) ak[d] = 0.5f;
        ck = -3.4657359028f - 0.5f * msq;   // log(1/32) - 0.5*sum mu^2
    } else {
        const float* pb = prmIn + (size_t)b * 1056;
        ck = pb[k];
#pragma unroll
        for (int d = 0; d < DD; d++) {
            ak[d] = pb[(1 + d) * 32 + k];
            bk[d] = pb[(17 + d) * 32 + k];
        }
    }

    float aN = 0.f, aSx[DD], aSxx[DD];
#pragma unroll
    for (int d = 0; d < DD; d++) { aSx[d] = 0.f; aSxx[d] = 0.f; }

    const int NITER = (MODE == 0) ? 8 : 4;
#pragma unroll 4
    for (int i = 0; i < NITER; i++) {
        const int n = chunk * ((MODE == 0) ? 64 : 32) + i * 8 + wave * 2 + jj;
        const float4* xp = (const float4*)(x + ((size_t)b * NN + n) * DD);
        float xv[DD];
#pragma unroll
        for (int q = 0; q < 4; q++) {
            float4 v = xp[q];
            xv[q*4+0]=v.x; xv[q*4+1]=v.y; xv[q*4+2]=v.z; xv[q*4+3]=v.w;
        }
        float logit = ck;
#pragma unroll
        for (int d = 0; d < DD; d++) {
            float t1 = fmaf(-ak[d], xv[d], bk[d]);
            logit = fmaf(xv[d], t1, logit);
        }
        float m = logit;
#pragma unroll
        for (int off = 1; off < 32; off <<= 1) m = fmaxf(m, __shfl_xor(m, off));
        float e = __expf(logit - m);
        float ssum = e;
#pragma unroll
        for (int off = 1; off < 32; off <<= 1) ssum += __shfl_xor(ssum, off);
        float g = e * __builtin_amdgcn_rcpf(ssum);

        if (MODE == 1) {
            Rout[((size_t)b * NN + n) * KK + k] = g;  // coalesced per half-wave
        } else {
            aN += g;
#pragma unroll
            for (int d = 0; d < DD; d++) {
                aSx[d] = fmaf(g, xv[d], aSx[d]);
                aSxx[d] = fmaf(g * xv[d], xv[d], aSxx[d]);
            }
        }
    }

    if (MODE == 0) {
        __shared__ float red[4][KK * 33];
        aN += __shfl_xor(aN, 32);
#pragma unroll
        for (int d = 0; d < DD; d++) {
            aSx[d] += __shfl_xor(aSx[d], 32);
            aSxx[d] += __shfl_xor(aSxx[d], 32);
        }
        if (jj == 0) {
            red[wave][k * 33 + 0] = aN;
#pragma unroll
            for (int d = 0; d < DD; d++) {
                red[wave][k * 33 + 1 + d] = aSx[d];
                red[wave][k * 33 + 17 + d] = aSxx[d];
            }
        }
        __syncthreads();
        float* outp = partOut + (size_t)(b * PART_C + chunk) * PART_STRIDE;
        for (int idx = tid; idx < KK * 33; idx += 256) {
            int kk = idx & 31, j = idx >> 5;
            float v = red[0][kk * 33 + j] + red[1][kk * 33 + j] +
                      red[2][kk * 33 + j] + red[3][kk * 33 + j];
            outp[idx] = v;
        }
    }
}

static __device__ __forceinline__ void xpack_body(int blk, const float* __restrict__ x,
                                                  ushort* __restrict__ xpk) {
    int idx = blk * 256 + threadIdx.x;   // n*64 + l
    int n = idx >> 6, l = idx & 63;
    int b = l & 31, e0 = (l >> 5) * 8;
    const float4* xp = (const float4*)(x + ((size_t)b * NN + n) * DD + e0);
    float4 a = xp[0], c = xp[1];
    ushort* o = xpk + (size_t)idx * 8;
    o[0]=f2bf(a.x); o[1]=f2bf(a.y); o[2]=f2bf(a.z); o[3]=f2bf(a.w);
    o[4]=f2bf(c.x); o[5]=f2bf(c.y); o[6]=f2bf(c.z); o[7]=f2bf(c.w);
}

__global__ __launch_bounds__(256, 4) void k_fused1(
    const float* __restrict__ x, const float* __restrict__ mu0,
    float* __restrict__ partOut, ushort* __restrict__ xpk) {
    if (blockIdx.x < 1024)
        estep_body<0, 1>(blockIdx.x, x, mu0, nullptr, partOut, nullptr);
    else
        xpack_body(blockIdx.x - 1024, x, xpk);
}

template <int MODE>
__global__ __launch_bounds__(256, 4) void k_estep(
    const float* __restrict__ x, const float* __restrict__ prmIn,
    float* __restrict__ partOut, float* __restrict__ Rout) {
    estep_body<MODE, 0>(blockIdx.x, x, nullptr, prmIn, partOut, Rout);
}

// transpose R[b][n][k] -> R3[n][k][hi][pos]; 512 blocks x 4 n (2 blocks/CU).
__global__ __launch_bounds__(256) void k_transp(const float* __restrict__ R,
                                                float* __restrict__ R3) {
    __shared__ float lds[32 * 4 * 32];  // [b][nj][k], 16 KB
    const int t = threadIdx.x;
    const int n0 = blockIdx.x * 4;
#pragma unroll
    for (int c = 0; c < 4; c++) {
        int f = c * 256 + t;             // float4 index (1024 total)
        int b = f >> 5, rem = f & 31;
        int nj = rem >> 3, k4 = rem & 7;
        float4 v = *(const float4*)(R + ((size_t)b * NN + n0 + nj) * KK + k4 * 4);
        *(float4*)&lds[(b * 4 + nj) * 32 + k4 * 4] = v;
    }
    __syncthreads();
#pragma unroll
    for (int c = 0; c < 4; c++) {
        int o = c * 256 + t;             // output float4 index
        int a4 = o * 4;
        int nl = a4 >> 10, w = a4 & 1023;
        int k = w >> 5, hi = (w >> 4) & 1, p = (w >> 2) & 3;
        int bb = 8 * p + 4 * hi;         // pos 4p+e -> b = e + 8p + 4hi
        float4 v;
        v.x = lds[((bb + 0) * 4 + nl) * 32 + k];
        v.y = lds[((bb + 1) * 4 + nl) * 32 + k];
        v.z = lds[((bb + 2) * 4 + nl) * 32 + k];
        v.w = lds[((bb + 3) * 4 + nl) * 32 + k];
        *(float4*)(R3 + (size_t)n0 * 1024 + a4) = v;
    }
}

// caps v9: v8 + i-loop unroll 4 (deeper MLP for the latency-bound W/r stream)
// + HW bf16 cvt for W (compiler pairs to v_cvt_pk_bf16_f32).
__global__ __launch_bounds__(256, 4) void k_caps(
    const float* __restrict__ W, const ushort* __restrict__ xpk,
    const float* __restrict__ R3, float* __restrict__ s) {
    const int tid = threadIdx.x;
    const int wv = tid >> 6, l = tid & 63;
    const int chunk = blockIdx.x >> 2, tg = blockIdx.x & 3;
    const int t = tg * 4 + wv;          // kd-tile 0..15
    const int col = l & 31, hi = l >> 5;
    const int kq = (l >> 4) & 1;        // k = 2t + kq
    float* sc = s + (size_t)chunk * (BN * KK * DD);

    float sacc[16];
#pragma unroll
    for (int q = 0; q < 16; q++) sacc[q] = 0.f;
    const f32x16 zacc = {0.f,0.f,0.f,0.f, 0.f,0.f,0.f,0.f,
                         0.f,0.f,0.f,0.f, 0.f,0.f,0.f,0.f};

#pragma unroll 4
    for (int i = 0; i < 8; i++) {
        const int n = chunk * 8 + i;
        bf16x8 af = *(const bf16x8*)(xpk + ((size_t)n * 64 + l) * 8);
        const float4* wp = (const float4*)(W + (((size_t)n * 512 + t * 32 + col) * DD) + hi * 8);
        float4 wlo = wp[0], whi = wp[1];
        bf16x8 bfr;
        bfr[0]=f2bfs(wlo.x); bfr[1]=f2bfs(wlo.y);
        bfr[2]=f2bfs(wlo.z); bfr[3]=f2bfs(wlo.w);
        bfr[4]=f2bfs(whi.x); bfr[5]=f2bfs(whi.y);
        bfr[6]=f2bfs(whi.z); bfr[7]=f2bfs(whi.w);
        const float4* rp = (const float4*)(R3 + (((size_t)n * KK + 2 * t + kq) * 2 + hi) * 16);
        float4 r0 = rp[0], r1 = rp[1], r2 = rp[2], r3v = rp[3];

        f32x16 D = __builtin_amdgcn_mfma_f32_32x32x16_bf16(af, bfr, zacc, 0, 0, 0);

        sacc[0]  = fmaf(r0.x,  D[0],  sacc[0]);
        sacc[1]  = fmaf(r0.y,  D[1],  sacc[1]);
        sacc[2]  = fmaf(r0.z,  D[2],  sacc[2]);
        sacc[3]  = fmaf(r0.w,  D[3],  sacc[3]);
        sacc[4]  = fmaf(r1.x,  D[4],  sacc[4]);
        sacc[5]  = fmaf(r1.y,  D[5],  sacc[5]);
        sacc[6]  = fmaf(r1.z,  D[6],  sacc[6]);
        sacc[7]  = fmaf(r1.w,  D[7],  sacc[7]);
        sacc[8]  = fmaf(r2.x,  D[8],  sacc[8]);
        sacc[9]  = fmaf(r2.y,  D[9],  sacc[9]);
        sacc[10] = fmaf(r2.z,  D[10], sacc[10]);
        sacc[11] = fmaf(r2.w,  D[11], sacc[11]);
        sacc[12] = fmaf(r3v.x, D[12], sacc[12]);
        sacc[13] = fmaf(r3v.y, D[13], sacc[13]);
        sacc[14] = fmaf(r3v.z, D[14], sacc[14]);
        sacc[15] = fmaf(r3v.w, D[15], sacc[15]);
    }

    const int kd = t * 32 + col;
#pragma unroll
    for (int q = 0; q < 16; q++) {
        const int b = (q & 3) + 8 * (q >> 2) + 4 * hi;  // verified C/D row map
        sc[(size_t)b * (KK * DD) + kd] = sacc[q];       // disjoint plain store
    }
}

// squash: block = 64 outputs x 4 copy-quarters (256 thr); 4 waves/CU.
__global__ __launch_bounds__(256) void k_squash(const float* __restrict__ s,
                                                float* __restrict__ out) {
    __shared__ float sq[256];
    const int t = threadIdx.x;
    const int il = t & 63, qt = t >> 6;
    const int idx = blockIdx.x * 64 + il;   // 16384 = BN*KK*DD
    float v = 0.f;
#pragma unroll 16
    for (int c = qt * 64; c < qt * 64 + 64; c++)
        v += s[(size_t)c * (BN * KK * DD) + idx];
    sq[t] = v;
    __syncthreads();
    if (qt == 0) {
        v = sq[il] + sq[il + 64] + sq[il + 128] + sq[il + 192];
        float ss = v * v;
#pragma unroll
        for (int off = 1; off < 16; off <<= 1) ss += __shfl_xor(ss, off);
        ss += 1e-7f;
        float scale = sqrtf(ss) / (1.0f + ss);
        out[idx] = v * scale;
    }
}

extern "C" void kernel_launch(void* const* d_in, const int* in_sizes, int n_in,
                              void* d_out, int out_size, void* d_ws, size_t ws_size,
                              hipStream_t stream) {
    const float* x   = (const float*)d_in[0];
    const float* W   = (const float*)d_in[1];
    const float* mu0 = (const float*)d_in[2];
    float* ws    = (float*)d_ws;
    float* partA = ws;
    float* partB = ws + 1081344;
    float* prmA  = ws + 2162688;
    float* prmB  = ws + 2196480;
    float* R     = ws + 2230272;
    float* s     = ws;            // overlays partA/partB/prm/R (all dead by caps)
    float* R3    = ws + 4327424;
    ushort* xpk  = (ushort*)(ws + 6424576);

    // 1: EM iter1 partials (grid 1024) + x bf16 pack (512), fused
    k_fused1<<<1536, 256, 0, stream>>>(x, mu0, partA, xpk);
    // 2: reduce 32 partials -> ready params (iter2)
    k_param<<<32, 256, 0, stream>>>(partA, prmA);
    // 3: EM iter2 (reads prmA, grid 1024) -> partB
    k_estep<0><<<1024, 256, 0, stream>>>(x, prmA, partB, nullptr);
    // 4: reduce 32 partials -> ready params (iter3)
    k_param<<<32, 256, 0, stream>>>(partB, prmB);
    // 5: EM iter3 (reads prmB, grid 2048) -> R
    k_estep<1><<<2048, 256, 0, stream>>>(x, prmB, nullptr, R);
    // 6: transpose R -> fragment-ordered R3 (512 blocks x 4 n)
    k_transp<<<512, 256, 0, stream>>>(R, R3);
    // 7: caps einsum (MFMA v9), plain stores into per-chunk s copies
    k_caps<<<1024, 256, 0, stream>>>(W, xpk, R3, s);
    // 8: reduce 256 copies + squash (256 blocks x 4 waves)
    k_squash<<<256, 256, 0, stream>>>(s, (float*)d_out);
}